// Round 1
// baseline (328.425 us; speedup 1.0000x reference)
//
#include <hip/hip_runtime.h>

#define BB 16
#define HW 4096
#define DIMC 256
#define NHEAD 8
#define CPH 8
#define NQKV 192
#define SCALE 0.17677669529663687f

// ---------------- K1: qkv GEMM ----------------
// qkvt[b][j][s] = sum_k qkv_w[j][k] * x[b][k*4096+s] + qkv_b[j]
// x is already (B, 256, 4096) channel-planar in memory (flat reinterpretation).
__global__ __launch_bounds__(256) void qkv_kernel(const float* __restrict__ x,
                                                  const float* __restrict__ qw,
                                                  const float* __restrict__ qb,
                                                  float* __restrict__ qkvt) {
  __shared__ float Xs[32][64];     // k-chunk x spatial tile
  __shared__ float Ws[192][34];    // all j x k-chunk (pad 34 for bank spread / b64 align)
  const int b = blockIdx.y;
  const int s0 = blockIdx.x * 64;
  const int tid = threadIdx.x;
  const int sgrp = tid & 15, jgrp = tid >> 4;
  const int sl = sgrp * 4;
  const int j0 = jgrp * 12;

  float acc[12][4];
#pragma unroll
  for (int jj = 0; jj < 12; ++jj) {
    float bias = qb[j0 + jj];
    acc[jj][0] = bias; acc[jj][1] = bias; acc[jj][2] = bias; acc[jj][3] = bias;
  }
  const float* xb = x + (size_t)b * (DIMC * HW);

  for (int kc = 0; kc < 256; kc += 32) {
    __syncthreads();
    // stage X chunk: 32 k x 64 s = 512 float4, 2 per thread
#pragma unroll
    for (int i = 0; i < 2; ++i) {
      int idx = tid + i * 256;
      int kl = idx >> 4, f = idx & 15;
      float4 v = *(const float4*)&xb[(size_t)(kc + kl) * HW + s0 + f * 4];
      *(float4*)&Xs[kl][f * 4] = v;
    }
    // stage W chunk: 192 rows x 32 cols = 1536 float4, 6 per thread
#pragma unroll
    for (int i = 0; i < 6; ++i) {
      int idx = tid + i * 256;
      int j = idx >> 3, f = idx & 7;
      float4 v = *(const float4*)&qw[j * 256 + kc + f * 4];
      Ws[j][f * 4 + 0] = v.x; Ws[j][f * 4 + 1] = v.y;
      Ws[j][f * 4 + 2] = v.z; Ws[j][f * 4 + 3] = v.w;
    }
    __syncthreads();
#pragma unroll 4
    for (int k = 0; k < 32; k += 2) {
      float4 x0 = *(const float4*)&Xs[k][sl];
      float4 x1 = *(const float4*)&Xs[k + 1][sl];
#pragma unroll
      for (int jj = 0; jj < 12; ++jj) {
        float2 wv = *(const float2*)&Ws[j0 + jj][k];
        acc[jj][0] = fmaf(wv.x, x0.x, acc[jj][0]);
        acc[jj][1] = fmaf(wv.x, x0.y, acc[jj][1]);
        acc[jj][2] = fmaf(wv.x, x0.z, acc[jj][2]);
        acc[jj][3] = fmaf(wv.x, x0.w, acc[jj][3]);
        acc[jj][0] = fmaf(wv.y, x1.x, acc[jj][0]);
        acc[jj][1] = fmaf(wv.y, x1.y, acc[jj][1]);
        acc[jj][2] = fmaf(wv.y, x1.z, acc[jj][2]);
        acc[jj][3] = fmaf(wv.y, x1.w, acc[jj][3]);
      }
    }
  }
  float* outb = qkvt + (size_t)b * (NQKV * HW);
#pragma unroll
  for (int jj = 0; jj < 12; ++jj) {
    float4 v = make_float4(acc[jj][0], acc[jj][1], acc[jj][2], acc[jj][3]);
    *(float4*)&outb[(size_t)(j0 + jj) * HW + s0 + sl] = v;
  }
}

// ---------------- K2: fused unfold + dwconv + rpb + softmax-attention ----------------
// Per (b, head, 16x16 pixel tile). One pixel per thread.
// k_cp = taps(kk)[p] + sum_rs w1[c*9+p][rs]*taps(kk)[rs] + dcb[c*9+p] + dc1b[c*9+p] + rpb[n][p]
// v_cp same with vv input and no rpb. logits_p = sum_c q_c*k_cp (q pre-scaled).
__global__ __launch_bounds__(256) void attn_kernel(const float* __restrict__ qkvt,
                                                   const float* __restrict__ dcb,
                                                   const float* __restrict__ w1,
                                                   const float* __restrict__ dc1b,
                                                   const float* __restrict__ rpb,
                                                   float* __restrict__ ao) {
  __shared__ float hal[2][8][18][20];  // kk / vv halo tiles, pad row to 20
  const int bn = blockIdx.x;   // b*8 + n
  const int tile = blockIdx.y; // 0..15
  const int b = bn >> 3, n = bn & 7;
  const int h0 = (tile >> 2) * 16, w0 = (tile & 3) * 16;
  const int tid = threadIdx.x;
  const int ly = tid >> 4, lx = tid & 15;
  const int s = (h0 + ly) * 64 + (w0 + lx);
  const float* fb = qkvt + ((size_t)b * NQKV + n * 24) * HW;

  // stage kk (t=8..15) and vv (t=16..23) halos: 2*8*18*18 = 5184 elements
  for (int e = tid; e < 5184; e += 256) {
    int buf = e / 2592;
    int rem = e - buf * 2592;
    int c = rem / 324;
    int yx = rem - c * 324;
    int y = yx / 18, xx = yx - y * 18;
    int gy = h0 - 1 + y, gx = w0 - 1 + xx;
    float v = 0.f;
    if ((unsigned)gy < 64u && (unsigned)gx < 64u)
      v = fb[(size_t)(8 + buf * 8 + c) * HW + gy * 64 + gx];
    hal[buf][c][y][xx] = v;
  }
  __syncthreads();

  float logit[9];
#pragma unroll
  for (int p = 0; p < 9; ++p) logit[p] = 0.f;
#pragma unroll
  for (int c = 0; c < 8; ++c) {
    float qc = SCALE * fb[(size_t)c * HW + s];
    float t[9];
#pragma unroll
    for (int dy = 0; dy < 3; ++dy)
#pragma unroll
      for (int dx = 0; dx < 3; ++dx)
        t[dy * 3 + dx] = hal[0][c][ly + dy][lx + dx];
#pragma unroll
    for (int p = 0; p < 9; ++p) {
      int o = c * 9 + p;
      float kcp = t[p] + dcb[o] + dc1b[o] + rpb[n * 9 + p];
#pragma unroll
      for (int rs = 0; rs < 9; ++rs)
        kcp = fmaf(w1[o * 9 + rs], t[rs], kcp);
      logit[p] = fmaf(qc, kcp, logit[p]);
    }
  }
  // softmax over 9
  float m = logit[0];
#pragma unroll
  for (int p = 1; p < 9; ++p) m = fmaxf(m, logit[p]);
  float a[9], den = 0.f;
#pragma unroll
  for (int p = 0; p < 9; ++p) { a[p] = __expf(logit[p] - m); den += a[p]; }
  float inv = 1.f / den;

  float* aob = ao + ((size_t)b * 64 + n * 8) * HW;
#pragma unroll
  for (int c = 0; c < 8; ++c) {
    float t[9];
#pragma unroll
    for (int dy = 0; dy < 3; ++dy)
#pragma unroll
      for (int dx = 0; dx < 3; ++dx)
        t[dy * 3 + dx] = hal[1][c][ly + dy][lx + dx];
    float oc = 0.f;
#pragma unroll
    for (int p = 0; p < 9; ++p) {
      int o = c * 9 + p;
      float vcp = t[p] + dcb[o] + dc1b[o];
#pragma unroll
      for (int rs = 0; rs < 9; ++rs)
        vcp = fmaf(w1[o * 9 + rs], t[rs], vcp);
      oc = fmaf(a[p], vcp, oc);
    }
    aob[(size_t)c * HW + s] = oc * inv;
  }
}

// ---------------- K3: proj GEMM ----------------
// out[b][d][s] = sum_j proj_w[d][j] * ao[b][j][s] + proj_b[d]
__global__ __launch_bounds__(256) void proj_kernel(const float* __restrict__ ao,
                                                   const float* __restrict__ pw,
                                                   const float* __restrict__ pb,
                                                   float* __restrict__ out) {
  __shared__ float As[64][64];   // j x spatial tile
  __shared__ float Pt[64][132];  // j x d-half (transposed, padded)
  const int b = blockIdx.y;
  const int s0 = (blockIdx.x >> 1) * 64;
  const int d00 = (blockIdx.x & 1) * 128;
  const int tid = threadIdx.x;
  const int sgrp = tid & 15, dgrp = tid >> 4;
  const int sl = sgrp * 4;
  const int dl = dgrp * 8;

  // stage ao tile: 64 j x 64 s = 1024 float4, 4/thread
#pragma unroll
  for (int i = 0; i < 4; ++i) {
    int idx = tid + i * 256;
    int kch = idx >> 4, f = idx & 15;
    float4 v = *(const float4*)&ao[((size_t)b * 64 + kch) * HW + s0 + f * 4];
    *(float4*)&As[kch][f * 4] = v;
  }
  // stage proj_w half transposed: 128 d x 64 j = 2048 float4, 8/thread
#pragma unroll
  for (int i = 0; i < 8; ++i) {
    int idx = tid + i * 256;
    int dd = idx >> 4, f = idx & 15;
    float4 v = *(const float4*)&pw[(size_t)(d00 + dd) * 64 + f * 4];
    Pt[f * 4 + 0][dd] = v.x; Pt[f * 4 + 1][dd] = v.y;
    Pt[f * 4 + 2][dd] = v.z; Pt[f * 4 + 3][dd] = v.w;
  }
  __syncthreads();

  float acc[8][4];
#pragma unroll
  for (int dd = 0; dd < 8; ++dd) {
    float bias = pb[d00 + dl + dd];
    acc[dd][0] = bias; acc[dd][1] = bias; acc[dd][2] = bias; acc[dd][3] = bias;
  }
#pragma unroll 4
  for (int k = 0; k < 64; ++k) {
    float4 xv = *(const float4*)&As[k][sl];
    float4 wa = *(const float4*)&Pt[k][dl];
    float4 wb = *(const float4*)&Pt[k][dl + 4];
    float wreg[8] = {wa.x, wa.y, wa.z, wa.w, wb.x, wb.y, wb.z, wb.w};
#pragma unroll
    for (int dd = 0; dd < 8; ++dd) {
      acc[dd][0] = fmaf(wreg[dd], xv.x, acc[dd][0]);
      acc[dd][1] = fmaf(wreg[dd], xv.y, acc[dd][1]);
      acc[dd][2] = fmaf(wreg[dd], xv.z, acc[dd][2]);
      acc[dd][3] = fmaf(wreg[dd], xv.w, acc[dd][3]);
    }
  }
#pragma unroll
  for (int dd = 0; dd < 8; ++dd) {
    float4 v = make_float4(acc[dd][0], acc[dd][1], acc[dd][2], acc[dd][3]);
    *(float4*)&out[((size_t)b << 20) + (size_t)(d00 + dl + dd) * HW + s0 + sl] = v;
  }
}

extern "C" void kernel_launch(void* const* d_in, const int* in_sizes, int n_in,
                              void* d_out, int out_size, void* d_ws, size_t ws_size,
                              hipStream_t stream) {
  (void)in_sizes; (void)n_in; (void)out_size; (void)ws_size;
  const float* x    = (const float*)d_in[0];
  // d_in[1]=H22, d_in[2]=W22, d_in[3]=relative_pos_index, d_in[4]=relative_coords_table (unused)
  const float* qw   = (const float*)d_in[5];
  const float* qb   = (const float*)d_in[6];
  const float* dcb  = (const float*)d_in[7];
  const float* w1   = (const float*)d_in[8];
  const float* dc1b = (const float*)d_in[9];
  const float* rpb  = (const float*)d_in[10];
  const float* pw   = (const float*)d_in[11];
  const float* pb   = (const float*)d_in[12];

  float* qkvt = (float*)d_ws;                                   // (B,192,4096) = 50.3 MB
  float* ao   = (float*)((char*)d_ws + (size_t)BB * NQKV * HW * 4); // (B,64,4096) = 16.8 MB

  qkv_kernel<<<dim3(64, BB), 256, 0, stream>>>(x, qw, qb, qkvt);
  attn_kernel<<<dim3(BB * NHEAD, 16), 256, 0, stream>>>(qkvt, dcb, w1, dc1b, rpb, ao);
  proj_kernel<<<dim3(128, BB), 256, 0, stream>>>(ao, pw, pb, (float*)d_out);
}

// Round 2
// 308.478 us; speedup vs baseline: 1.0647x; 1.0647x over previous
//
#include <hip/hip_runtime.h>

#define BB 16
#define HW 4096
#define DIMC 256
#define NHEAD 8
#define CPH 8
#define NQKV 192
#define SCALE 0.17677669529663687f

// ---------------- K1: qkv GEMM ----------------
// qkvt[b][j][s] = sum_k qkv_w[j][k] * x[b][k*4096+s] + qkv_b[j]
// x is already (B, 256, 4096) channel-planar in memory (flat reinterpretation).
__global__ __launch_bounds__(256) void qkv_kernel(const float* __restrict__ x,
                                                  const float* __restrict__ qw,
                                                  const float* __restrict__ qb,
                                                  float* __restrict__ qkvt) {
  __shared__ float Xs[32][64];     // k-chunk x spatial tile
  __shared__ float Ws[192][34];    // all j x k-chunk (pad 34 for bank spread / b64 align)
  const int b = blockIdx.y;
  const int s0 = blockIdx.x * 64;
  const int tid = threadIdx.x;
  const int sgrp = tid & 15, jgrp = tid >> 4;
  const int sl = sgrp * 4;
  const int j0 = jgrp * 12;

  float acc[12][4];
#pragma unroll
  for (int jj = 0; jj < 12; ++jj) {
    float bias = qb[j0 + jj];
    acc[jj][0] = bias; acc[jj][1] = bias; acc[jj][2] = bias; acc[jj][3] = bias;
  }
  const float* xb = x + (size_t)b * (DIMC * HW);

  for (int kc = 0; kc < 256; kc += 32) {
    __syncthreads();
    // stage X chunk: 32 k x 64 s = 512 float4, 2 per thread
#pragma unroll
    for (int i = 0; i < 2; ++i) {
      int idx = tid + i * 256;
      int kl = idx >> 4, f = idx & 15;
      float4 v = *(const float4*)&xb[(size_t)(kc + kl) * HW + s0 + f * 4];
      *(float4*)&Xs[kl][f * 4] = v;
    }
    // stage W chunk: 192 rows x 32 cols = 1536 float4, 6 per thread
#pragma unroll
    for (int i = 0; i < 6; ++i) {
      int idx = tid + i * 256;
      int j = idx >> 3, f = idx & 7;
      float4 v = *(const float4*)&qw[j * 256 + kc + f * 4];
      Ws[j][f * 4 + 0] = v.x; Ws[j][f * 4 + 1] = v.y;
      Ws[j][f * 4 + 2] = v.z; Ws[j][f * 4 + 3] = v.w;
    }
    __syncthreads();
#pragma unroll 4
    for (int k = 0; k < 32; k += 2) {
      float4 x0 = *(const float4*)&Xs[k][sl];
      float4 x1 = *(const float4*)&Xs[k + 1][sl];
#pragma unroll
      for (int jj = 0; jj < 12; ++jj) {
        float2 wv = *(const float2*)&Ws[j0 + jj][k];
        acc[jj][0] = fmaf(wv.x, x0.x, acc[jj][0]);
        acc[jj][1] = fmaf(wv.x, x0.y, acc[jj][1]);
        acc[jj][2] = fmaf(wv.x, x0.z, acc[jj][2]);
        acc[jj][3] = fmaf(wv.x, x0.w, acc[jj][3]);
        acc[jj][0] = fmaf(wv.y, x1.x, acc[jj][0]);
        acc[jj][1] = fmaf(wv.y, x1.y, acc[jj][1]);
        acc[jj][2] = fmaf(wv.y, x1.z, acc[jj][2]);
        acc[jj][3] = fmaf(wv.y, x1.w, acc[jj][3]);
      }
    }
  }
  float* outb = qkvt + (size_t)b * (NQKV * HW);
#pragma unroll
  for (int jj = 0; jj < 12; ++jj) {
    float4 v = make_float4(acc[jj][0], acc[jj][1], acc[jj][2], acc[jj][3]);
    *(float4*)&outb[(size_t)(j0 + jj) * HW + s0 + sl] = v;
  }
}

// ---------------- K2 v2: wave-per-channel fused attn ----------------
// Block = 512 threads = 8 waves; wave w owns channel c=w of one (b,head).
// Tile = 4x16 pixels (lane = pixel). Per-wave A = I + W1_c (81 floats) lives
// in VGPRs for BOTH K and V phases -> inner loops are pure v_fmac_f32.
// Cross-channel logit reduction + softmax via LDS.
__global__ __launch_bounds__(512, 4) void attn_kernel(const float* __restrict__ qkvt,
                                                      const float* __restrict__ dcb,
                                                      const float* __restrict__ w1,
                                                      const float* __restrict__ dc1b,
                                                      const float* __restrict__ rpb,
                                                      float* __restrict__ ao) {
  __shared__ float hal[16][6][20];            // [0-7: kk, 8-15: vv][y][x] halo, pad 20
  __shared__ float plog[8][9][64];            // per-channel partial logits
  __shared__ float att[9][64];                // softmax weights
  __shared__ __align__(16) float wA[8][84];   // staged w1, row padded for b128
  __shared__ float dsum[72];                  // dcb + dc1b
  __shared__ float rpbn[9];

  const int bn = blockIdx.x;   // b*8 + n
  const int tile = blockIdx.y; // 0..63 : 16 y-tiles x 4 x-tiles
  const int b = bn >> 3, n = bn & 7;
  const int h0 = (tile >> 2) * 4, w0 = (tile & 3) * 16;
  const int tid = threadIdx.x;
  const int wv = tid >> 6, lane = tid & 63;
  const int ly = lane >> 4, lx = lane & 15;
  const int s = (h0 + ly) * 64 + (w0 + lx);
  const float* fb = qkvt + ((size_t)b * NQKV + n * 24) * HW;
  const int c = wv;

  // stage kk/vv halos: 16 chan-bufs x 6 x 18 = 1728 elements
  for (int e = tid; e < 1728; e += 512) {
    int cb = e / 108;
    int pos = e - cb * 108;
    int y = pos / 18, xx = pos - y * 18;
    int gy = h0 - 1 + y, gx = w0 - 1 + xx;
    float v = 0.f;
    if ((unsigned)gy < 64u && (unsigned)gx < 64u)
      v = fb[(size_t)(8 + cb) * HW + gy * 64 + gx];
    hal[cb][y][xx] = v;
  }
  // stage coefficients (coalesced, once per block)
  for (int e = tid; e < 648; e += 512) {
    int cc = e / 81;
    wA[cc][e - cc * 81] = w1[e];
  }
  if (tid < 72) dsum[tid] = dcb[tid] + dc1b[tid];
  else if (tid >= 128 && tid < 137) rpbn[tid - 128] = rpb[n * 9 + (tid - 128)];

  float qc = SCALE * fb[(size_t)c * HW + s];  // independent global load, pre-sync
  __syncthreads();

  // per-wave coefficients -> VGPRs (broadcast LDS reads, conflict-free)
  float Af[81];
#pragma unroll
  for (int i = 0; i < 20; ++i) {
    float4 v = *(const float4*)&wA[c][i * 4];
    Af[i * 4 + 0] = v.x; Af[i * 4 + 1] = v.y;
    Af[i * 4 + 2] = v.z; Af[i * 4 + 3] = v.w;
  }
  Af[80] = wA[c][80];
#pragma unroll
  for (int p = 0; p < 9; ++p) Af[p * 9 + p] += 1.f;

  // ---- K phase: partial logits for channel c ----
  {
    float t[9];
#pragma unroll
    for (int dy = 0; dy < 3; ++dy)
#pragma unroll
      for (int dx = 0; dx < 3; ++dx)
        t[dy * 3 + dx] = hal[c][ly + dy][lx + dx];
#pragma unroll
    for (int p = 0; p < 9; ++p) {
      float kcp = dsum[c * 9 + p] + rpbn[p];
#pragma unroll
      for (int rs = 0; rs < 9; ++rs)
        kcp = fmaf(Af[p * 9 + rs], t[rs], kcp);
      plog[c][p][lane] = qc * kcp;
    }
  }
  __syncthreads();

  // ---- reduce over channels: 576 (p,px) items ----
  for (int it = tid; it < 576; it += 512) {
    int p = it >> 6, px = it & 63;
    float sum = plog[0][p][px] + plog[1][p][px] + plog[2][p][px] + plog[3][p][px] +
                plog[4][p][px] + plog[5][p][px] + plog[6][p][px] + plog[7][p][px];
    plog[0][p][px] = sum;
  }
  __syncthreads();

  // ---- softmax (wave 0, lane = pixel) ----
  if (wv == 0) {
    float lg[9];
#pragma unroll
    for (int p = 0; p < 9; ++p) lg[p] = plog[0][p][lane];
    float m = lg[0];
#pragma unroll
    for (int p = 1; p < 9; ++p) m = fmaxf(m, lg[p]);
    float e[9], den = 0.f;
#pragma unroll
    for (int p = 0; p < 9; ++p) { e[p] = __expf(lg[p] - m); den += e[p]; }
    float inv = 1.f / den;
#pragma unroll
    for (int p = 0; p < 9; ++p) att[p][lane] = e[p] * inv;
  }
  __syncthreads();

  // ---- V phase: out_c = sum_p a_p * v_{c,p} ----
  {
    float t[9];
#pragma unroll
    for (int dy = 0; dy < 3; ++dy)
#pragma unroll
      for (int dx = 0; dx < 3; ++dx)
        t[dy * 3 + dx] = hal[8 + c][ly + dy][lx + dx];
    float aw[9];
#pragma unroll
    for (int p = 0; p < 9; ++p) aw[p] = att[p][lane];
    float oc = 0.f;
#pragma unroll
    for (int p = 0; p < 9; ++p) {
      float vcp = dsum[c * 9 + p];
#pragma unroll
      for (int rs = 0; rs < 9; ++rs)
        vcp = fmaf(Af[p * 9 + rs], t[rs], vcp);
      oc = fmaf(aw[p], vcp, oc);
    }
    ao[((size_t)b * 64 + n * 8 + c) * HW + s] = oc;
  }
}

// ---------------- K3: proj GEMM ----------------
// out[b][d][s] = sum_j proj_w[d][j] * ao[b][j][s] + proj_b[d]
__global__ __launch_bounds__(256) void proj_kernel(const float* __restrict__ ao,
                                                   const float* __restrict__ pw,
                                                   const float* __restrict__ pb,
                                                   float* __restrict__ out) {
  __shared__ float As[64][64];   // j x spatial tile
  __shared__ float Pt[64][132];  // j x d-half (transposed, padded)
  const int b = blockIdx.y;
  const int s0 = (blockIdx.x >> 1) * 64;
  const int d00 = (blockIdx.x & 1) * 128;
  const int tid = threadIdx.x;
  const int sgrp = tid & 15, dgrp = tid >> 4;
  const int sl = sgrp * 4;
  const int dl = dgrp * 8;

  // stage ao tile: 64 j x 64 s = 1024 float4, 4/thread
#pragma unroll
  for (int i = 0; i < 4; ++i) {
    int idx = tid + i * 256;
    int kch = idx >> 4, f = idx & 15;
    float4 v = *(const float4*)&ao[((size_t)b * 64 + kch) * HW + s0 + f * 4];
    *(float4*)&As[kch][f * 4] = v;
  }
  // stage proj_w half transposed: 128 d x 64 j = 2048 float4, 8/thread
#pragma unroll
  for (int i = 0; i < 8; ++i) {
    int idx = tid + i * 256;
    int dd = idx >> 4, f = idx & 15;
    float4 v = *(const float4*)&pw[(size_t)(d00 + dd) * 64 + f * 4];
    Pt[f * 4 + 0][dd] = v.x; Pt[f * 4 + 1][dd] = v.y;
    Pt[f * 4 + 2][dd] = v.z; Pt[f * 4 + 3][dd] = v.w;
  }
  __syncthreads();

  float acc[8][4];
#pragma unroll
  for (int dd = 0; dd < 8; ++dd) {
    float bias = pb[d00 + dl + dd];
    acc[dd][0] = bias; acc[dd][1] = bias; acc[dd][2] = bias; acc[dd][3] = bias;
  }
#pragma unroll 4
  for (int k = 0; k < 64; ++k) {
    float4 xv = *(const float4*)&As[k][sl];
    float4 wa = *(const float4*)&Pt[k][dl];
    float4 wb = *(const float4*)&Pt[k][dl + 4];
    float wreg[8] = {wa.x, wa.y, wa.z, wa.w, wb.x, wb.y, wb.z, wb.w};
#pragma unroll
    for (int dd = 0; dd < 8; ++dd) {
      acc[dd][0] = fmaf(wreg[dd], xv.x, acc[dd][0]);
      acc[dd][1] = fmaf(wreg[dd], xv.y, acc[dd][1]);
      acc[dd][2] = fmaf(wreg[dd], xv.z, acc[dd][2]);
      acc[dd][3] = fmaf(wreg[dd], xv.w, acc[dd][3]);
    }
  }
#pragma unroll
  for (int dd = 0; dd < 8; ++dd) {
    float4 v = make_float4(acc[dd][0], acc[dd][1], acc[dd][2], acc[dd][3]);
    *(float4*)&out[((size_t)b << 20) + (size_t)(d00 + dl + dd) * HW + s0 + sl] = v;
  }
}

extern "C" void kernel_launch(void* const* d_in, const int* in_sizes, int n_in,
                              void* d_out, int out_size, void* d_ws, size_t ws_size,
                              hipStream_t stream) {
  (void)in_sizes; (void)n_in; (void)out_size; (void)ws_size;
  const float* x    = (const float*)d_in[0];
  const float* qw   = (const float*)d_in[5];
  const float* qb   = (const float*)d_in[6];
  const float* dcb  = (const float*)d_in[7];
  const float* w1   = (const float*)d_in[8];
  const float* dc1b = (const float*)d_in[9];
  const float* rpb  = (const float*)d_in[10];
  const float* pw   = (const float*)d_in[11];
  const float* pb   = (const float*)d_in[12];

  float* qkvt = (float*)d_ws;                                      // (B,192,4096)
  float* ao   = (float*)((char*)d_ws + (size_t)BB * NQKV * HW * 4); // (B,64,4096)

  qkv_kernel<<<dim3(64, BB), 256, 0, stream>>>(x, qw, qb, qkvt);
  attn_kernel<<<dim3(BB * NHEAD, 64), 512, 0, stream>>>(qkvt, dcb, w1, dc1b, rpb, ao);
  proj_kernel<<<dim3(128, BB), 256, 0, stream>>>(ao, pw, pb, (float*)d_out);
}

// Round 3
// 249.561 us; speedup vs baseline: 1.3160x; 1.2361x over previous
//
#include <hip/hip_runtime.h>

#define BB 16
#define HW 4096
#define DIMC 256
#define NHEAD 8
#define CPH 8
#define NQKV 192
#define SCALE 0.17677669529663687f

typedef __attribute__((ext_vector_type(8))) short bf16x8;
typedef __attribute__((ext_vector_type(4))) float f32x4;

__device__ inline unsigned short f2b(float f) {
  union { float f; unsigned int u; } x; x.f = f;
  unsigned int r = x.u + 0x7FFFu + ((x.u >> 16) & 1u);
  return (unsigned short)(r >> 16);
}
__device__ inline float b2f(unsigned short u) {
  union { unsigned int u; float f; } x; x.u = ((unsigned int)u) << 16;
  return x.f;
}
__device__ inline void async_copy16(const void* g, void* l) {
  __builtin_amdgcn_global_load_lds((const __attribute__((address_space(1))) void*)g,
                                   (__attribute__((address_space(3))) void*)l, 16, 0, 0);
}

// ---------------- K0a: x (B,256k,4096s) fp32 -> xT (B,4096s,256k) bf16 ----------------
__global__ __launch_bounds__(256) void cast_xT(const float* __restrict__ x,
                                               unsigned short* __restrict__ xT) {
  __shared__ float Xs[64][69];  // pad 69: col-read banks (g8*8+sr) -> 2-way max
  const int b = blockIdx.z;
  const int k0 = blockIdx.y * 64;
  const int s0 = blockIdx.x * 64;
  const int tid = threadIdx.x;
  const float* xb = x + (size_t)b * (DIMC * HW);
#pragma unroll
  for (int i = 0; i < 4; ++i) {
    int idx = tid + i * 256;
    int kr = idx >> 4, f = idx & 15;
    float4 v = *(const float4*)&xb[(size_t)(k0 + kr) * HW + s0 + f * 4];
    Xs[kr][f * 4 + 0] = v.x; Xs[kr][f * 4 + 1] = v.y;
    Xs[kr][f * 4 + 2] = v.z; Xs[kr][f * 4 + 3] = v.w;
  }
  __syncthreads();
  unsigned short* ob = xT + (size_t)b * (HW * DIMC);
#pragma unroll
  for (int i = 0; i < 2; ++i) {
    int slot = tid + i * 256;
    int sr = slot >> 3, g8 = slot & 7;
    unsigned short pk[8];
#pragma unroll
    for (int j = 0; j < 8; ++j) pk[j] = f2b(Xs[g8 * 8 + j][sr]);
    *(uint4*)&ob[(size_t)(s0 + sr) * DIMC + k0 + g8 * 8] = *(uint4*)pk;
  }
}

// ---------------- K0b: qkv_w (192,256) fp32 -> bf16 in A-fragment-swizzled order ----------------
// layout: [(band*8 + c32)*64 + lane]*8 bf16; lane = g*16+m holds A[band*16+m][c32*32+g*8 .. +7]
__global__ __launch_bounds__(256) void cast_qw(const float* __restrict__ qw,
                                               unsigned short* __restrict__ qwf) {
  int t = blockIdx.x * 256 + threadIdx.x;  // 6144 total
  int lane = t & 63;
  int cell = t >> 6;  // band*8 + c32
  int m = lane & 15, g = lane >> 4;
  int band = cell >> 3, c32 = cell & 7;
  int j = band * 16 + m;
  int k = c32 * 32 + g * 8;
  unsigned short pk[8];
#pragma unroll
  for (int i = 0; i < 8; ++i) pk[i] = f2b(qw[j * 256 + k + i]);
  *(uint4*)&qwf[(size_t)t * 8] = *(uint4*)pk;
}

// ---------------- K1: qkv GEMM via bf16 MFMA ----------------
// C(192j x 128s per block) = qw(192x256) * x^T(256 x 128s). 4 waves; wave owns 3 j-bands x all 8 s-tiles.
// B staged full-K in LDS (64KB) via global_load_lds w=16, XOR-swizzled chunks for bank balance.
__global__ __launch_bounds__(256) void qkv_mfma(const unsigned short* __restrict__ xT,
                                                const unsigned short* __restrict__ qwf,
                                                const float* __restrict__ qb,
                                                unsigned short* __restrict__ qkvt) {
  __shared__ unsigned short Bs[128 * 256];  // [s_row][k], row=512B, chunks XOR-swizzled
  const int b = blockIdx.y;
  const int s_blk = blockIdx.x * 128;
  const int tid = threadIdx.x;
  const int wave = tid >> 6, lane = tid & 63;

  // stage: 64 instructions total, 16 per wave; instr i covers rows {2i, 2i+1}
  {
    const int row_in = lane >> 5, cst = lane & 31;
#pragma unroll
    for (int ii = 0; ii < 16; ++ii) {
      int i = wave * 16 + ii;
      int s_row = 2 * i + row_in;
      int mem_chunk = (cst & 24) | ((cst ^ s_row) & 7);
      const unsigned short* src =
          xT + ((size_t)b * HW + s_blk + s_row) * DIMC + mem_chunk * 8;
      async_copy16(src, (char*)Bs + i * 1024);
    }
  }
  __syncthreads();

  f32x4 acc[3][8];
#pragma unroll
  for (int t = 0; t < 3; ++t)
#pragma unroll
    for (int st = 0; st < 8; ++st) acc[t][st] = (f32x4){0.f, 0.f, 0.f, 0.f};

  const int n = lane & 15, g = lane >> 4;
#pragma unroll
  for (int c32 = 0; c32 < 8; ++c32) {
    bf16x8 af[3];
#pragma unroll
    for (int t = 0; t < 3; ++t) {
      int band = wave * 3 + t;
      af[t] = *(const bf16x8*)(qwf + ((size_t)(band * 8 + c32) * 64 + lane) * 8);
    }
#pragma unroll
    for (int st = 0; st < 8; ++st) {
      int s_row = st * 16 + n;
      int mc = c32 * 4 + g;
      int stc = (mc & 24) | ((mc ^ s_row) & 7);
      bf16x8 bf = *(const bf16x8*)&Bs[s_row * 256 + stc * 8];
#pragma unroll
      for (int t = 0; t < 3; ++t)
        acc[t][st] = __builtin_amdgcn_mfma_f32_16x16x32_bf16(af[t], bf, acc[t][st], 0, 0, 0);
    }
  }

  // epilogue: D col = lane&15 (s), row = g*4+r (j within band)  [m89-verified mapping]
  unsigned short* ob = qkvt + (size_t)b * (NQKV * HW);
#pragma unroll
  for (int t = 0; t < 3; ++t) {
    int j0 = (wave * 3 + t) * 16 + g * 4;
#pragma unroll
    for (int st = 0; st < 8; ++st) {
      int s = s_blk + st * 16 + n;
#pragma unroll
      for (int r = 0; r < 4; ++r) {
        float v = acc[t][st][r] + qb[j0 + r];
        ob[(size_t)(j0 + r) * HW + s] = f2b(v);
      }
    }
  }
}

// ---------------- K2: wave-per-channel fused attn (bf16 qkvt input) ----------------
__global__ __launch_bounds__(512, 2) void attn_kernel(const unsigned short* __restrict__ qkvt,
                                                      const float* __restrict__ dcb,
                                                      const float* __restrict__ w1,
                                                      const float* __restrict__ dc1b,
                                                      const float* __restrict__ rpb,
                                                      float* __restrict__ ao) {
  __shared__ float hal[16][6][20];
  __shared__ float plog[8][9][64];
  __shared__ float att[9][64];
  __shared__ __align__(16) float wA[8][84];
  __shared__ float dsum[72];
  __shared__ float rpbn[9];

  const int bn = blockIdx.x;
  const int tile = blockIdx.y;
  const int b = bn >> 3, n = bn & 7;
  const int h0 = (tile >> 2) * 4, w0 = (tile & 3) * 16;
  const int tid = threadIdx.x;
  const int wv = tid >> 6, lane = tid & 63;
  const int ly = lane >> 4, lx = lane & 15;
  const int s = (h0 + ly) * 64 + (w0 + lx);
  const unsigned short* fb = qkvt + ((size_t)b * NQKV + n * 24) * HW;
  const int c = wv;

  for (int e = tid; e < 1728; e += 512) {
    int cb = e / 108;
    int pos = e - cb * 108;
    int y = pos / 18, xx = pos - y * 18;
    int gy = h0 - 1 + y, gx = w0 - 1 + xx;
    float v = 0.f;
    if ((unsigned)gy < 64u && (unsigned)gx < 64u)
      v = b2f(fb[(size_t)(8 + cb) * HW + gy * 64 + gx]);
    hal[cb][y][xx] = v;
  }
  for (int e = tid; e < 648; e += 512) {
    int cc = e / 81;
    wA[cc][e - cc * 81] = w1[e];
  }
  if (tid < 72) dsum[tid] = dcb[tid] + dc1b[tid];
  else if (tid >= 128 && tid < 137) rpbn[tid - 128] = rpb[n * 9 + (tid - 128)];

  float qc = SCALE * b2f(fb[(size_t)c * HW + s]);
  __syncthreads();

  float Af[81];
#pragma unroll
  for (int i = 0; i < 20; ++i) {
    float4 v = *(const float4*)&wA[c][i * 4];
    Af[i * 4 + 0] = v.x; Af[i * 4 + 1] = v.y;
    Af[i * 4 + 2] = v.z; Af[i * 4 + 3] = v.w;
  }
  Af[80] = wA[c][80];
#pragma unroll
  for (int p = 0; p < 9; ++p) Af[p * 9 + p] += 1.f;

  {
    float t[9];
#pragma unroll
    for (int dy = 0; dy < 3; ++dy)
#pragma unroll
      for (int dx = 0; dx < 3; ++dx)
        t[dy * 3 + dx] = hal[c][ly + dy][lx + dx];
#pragma unroll
    for (int p = 0; p < 9; ++p) {
      float kcp = dsum[c * 9 + p] + rpbn[p];
#pragma unroll
      for (int rs = 0; rs < 9; ++rs)
        kcp = fmaf(Af[p * 9 + rs], t[rs], kcp);
      plog[c][p][lane] = qc * kcp;
    }
  }
  __syncthreads();

  for (int it = tid; it < 576; it += 512) {
    int p = it >> 6, px = it & 63;
    float sum = plog[0][p][px] + plog[1][p][px] + plog[2][p][px] + plog[3][p][px] +
                plog[4][p][px] + plog[5][p][px] + plog[6][p][px] + plog[7][p][px];
    plog[0][p][px] = sum;
  }
  __syncthreads();

  if (wv == 0) {
    float lg[9];
#pragma unroll
    for (int p = 0; p < 9; ++p) lg[p] = plog[0][p][lane];
    float m = lg[0];
#pragma unroll
    for (int p = 1; p < 9; ++p) m = fmaxf(m, lg[p]);
    float e[9], den = 0.f;
#pragma unroll
    for (int p = 0; p < 9; ++p) { e[p] = __expf(lg[p] - m); den += e[p]; }
    float inv = 1.f / den;
#pragma unroll
    for (int p = 0; p < 9; ++p) att[p][lane] = e[p] * inv;
  }
  __syncthreads();

  {
    float t[9];
#pragma unroll
    for (int dy = 0; dy < 3; ++dy)
#pragma unroll
      for (int dx = 0; dx < 3; ++dx)
        t[dy * 3 + dx] = hal[8 + c][ly + dy][lx + dx];
    float aw[9];
#pragma unroll
    for (int p = 0; p < 9; ++p) aw[p] = att[p][lane];
    float oc = 0.f;
#pragma unroll
    for (int p = 0; p < 9; ++p) {
      float vcp = dsum[c * 9 + p];
#pragma unroll
      for (int rs = 0; rs < 9; ++rs)
        vcp = fmaf(Af[p * 9 + rs], t[rs], vcp);
      oc = fmaf(aw[p], vcp, oc);
    }
    ao[((size_t)b * 64 + n * 8 + c) * HW + s] = oc;
  }
}

// ---------------- K3: proj GEMM (fp32) ----------------
__global__ __launch_bounds__(256) void proj_kernel(const float* __restrict__ ao,
                                                   const float* __restrict__ pw,
                                                   const float* __restrict__ pb,
                                                   float* __restrict__ out) {
  __shared__ float As[64][64];
  __shared__ float Pt[64][132];
  const int b = blockIdx.y;
  const int s0 = (blockIdx.x >> 1) * 64;
  const int d00 = (blockIdx.x & 1) * 128;
  const int tid = threadIdx.x;
  const int sgrp = tid & 15, dgrp = tid >> 4;
  const int sl = sgrp * 4;
  const int dl = dgrp * 8;

#pragma unroll
  for (int i = 0; i < 4; ++i) {
    int idx = tid + i * 256;
    int kch = idx >> 4, f = idx & 15;
    float4 v = *(const float4*)&ao[((size_t)b * 64 + kch) * HW + s0 + f * 4];
    *(float4*)&As[kch][f * 4] = v;
  }
#pragma unroll
  for (int i = 0; i < 8; ++i) {
    int idx = tid + i * 256;
    int dd = idx >> 4, f = idx & 15;
    float4 v = *(const float4*)&pw[(size_t)(d00 + dd) * 64 + f * 4];
    Pt[f * 4 + 0][dd] = v.x; Pt[f * 4 + 1][dd] = v.y;
    Pt[f * 4 + 2][dd] = v.z; Pt[f * 4 + 3][dd] = v.w;
  }
  __syncthreads();

  float acc[8][4];
#pragma unroll
  for (int dd = 0; dd < 8; ++dd) {
    float bias = pb[d00 + dl + dd];
    acc[dd][0] = bias; acc[dd][1] = bias; acc[dd][2] = bias; acc[dd][3] = bias;
  }
#pragma unroll 4
  for (int k = 0; k < 64; ++k) {
    float4 xv = *(const float4*)&As[k][sl];
    float4 wa = *(const float4*)&Pt[k][dl];
    float4 wb = *(const float4*)&Pt[k][dl + 4];
    float wreg[8] = {wa.x, wa.y, wa.z, wa.w, wb.x, wb.y, wb.z, wb.w};
#pragma unroll
    for (int dd = 0; dd < 8; ++dd) {
      acc[dd][0] = fmaf(wreg[dd], xv.x, acc[dd][0]);
      acc[dd][1] = fmaf(wreg[dd], xv.y, acc[dd][1]);
      acc[dd][2] = fmaf(wreg[dd], xv.z, acc[dd][2]);
      acc[dd][3] = fmaf(wreg[dd], xv.w, acc[dd][3]);
    }
  }
#pragma unroll
  for (int dd = 0; dd < 8; ++dd) {
    float4 v = make_float4(acc[dd][0], acc[dd][1], acc[dd][2], acc[dd][3]);
    *(float4*)&out[((size_t)b << 20) + (size_t)(d00 + dl + dd) * HW + s0 + sl] = v;
  }
}

extern "C" void kernel_launch(void* const* d_in, const int* in_sizes, int n_in,
                              void* d_out, int out_size, void* d_ws, size_t ws_size,
                              hipStream_t stream) {
  (void)in_sizes; (void)n_in; (void)out_size; (void)ws_size;
  const float* x    = (const float*)d_in[0];
  const float* qw   = (const float*)d_in[5];
  const float* qb   = (const float*)d_in[6];
  const float* dcb  = (const float*)d_in[7];
  const float* w1   = (const float*)d_in[8];
  const float* dc1b = (const float*)d_in[9];
  const float* rpb  = (const float*)d_in[10];
  const float* pw   = (const float*)d_in[11];
  const float* pb   = (const float*)d_in[12];

  // workspace layout (58.82 MB total; 67.1 MB was proven safe in R0):
  // [0, 25165824)            qkvt bf16 (B,192,4096)
  // [25165824, 58720256)     xT bf16 (B,4096,256)      -- dead after qkv_mfma
  // [25165824, 41943040)     ao fp32 (B,64,4096)       -- overlaps dead xT
  // [58720256, 58818560)     qwf bf16 swizzled weights
  unsigned short* qkvt = (unsigned short*)d_ws;
  unsigned short* xT   = (unsigned short*)((char*)d_ws + 25165824);
  float*          ao   = (float*)((char*)d_ws + 25165824);
  unsigned short* qwf  = (unsigned short*)((char*)d_ws + 58720256);

  cast_qw<<<24, 256, 0, stream>>>(qw, qwf);
  cast_xT<<<dim3(64, 4, BB), 256, 0, stream>>>(x, xT);
  qkv_mfma<<<dim3(32, BB), 256, 0, stream>>>(xT, qwf, qb, qkvt);
  attn_kernel<<<dim3(BB * NHEAD, 64), 512, 0, stream>>>(qkvt, dcb, w1, dc1b, rpb, ao);
  proj_kernel<<<dim3(128, BB), 256, 0, stream>>>(ao, pw, pb, (float*)d_out);
}

// Round 4
// 225.642 us; speedup vs baseline: 1.4555x; 1.1060x over previous
//
#include <hip/hip_runtime.h>

#define BB 16
#define HW 4096
#define DIMC 256
#define NHEAD 8
#define CPH 8
#define NQKV 192
#define SCALE 0.17677669529663687f

typedef __attribute__((ext_vector_type(8))) short bf16x8;
typedef __attribute__((ext_vector_type(4))) float f32x4;

__device__ inline unsigned short f2b(float f) {
  union { float f; unsigned int u; } x; x.f = f;
  unsigned int r = x.u + 0x7FFFu + ((x.u >> 16) & 1u);
  return (unsigned short)(r >> 16);
}
__device__ inline float b2f(unsigned short u) {
  union { unsigned int u; float f; } x; x.u = ((unsigned int)u) << 16;
  return x.f;
}
__device__ inline void async_copy16(const void* g, void* l) {
  __builtin_amdgcn_global_load_lds((const __attribute__((address_space(1))) void*)g,
                                   (__attribute__((address_space(3))) void*)l, 16, 0, 0);
}

// ---------------- K0a: x (B,256k,4096s) fp32 -> xT (B,4096s,256k) bf16 ----------------
__global__ __launch_bounds__(256) void cast_xT(const float* __restrict__ x,
                                               unsigned short* __restrict__ xT) {
  __shared__ float Xs[64][69];
  const int b = blockIdx.z;
  const int k0 = blockIdx.y * 64;
  const int s0 = blockIdx.x * 64;
  const int tid = threadIdx.x;
  const float* xb = x + (size_t)b * (DIMC * HW);
#pragma unroll
  for (int i = 0; i < 4; ++i) {
    int idx = tid + i * 256;
    int kr = idx >> 4, f = idx & 15;
    float4 v = *(const float4*)&xb[(size_t)(k0 + kr) * HW + s0 + f * 4];
    Xs[kr][f * 4 + 0] = v.x; Xs[kr][f * 4 + 1] = v.y;
    Xs[kr][f * 4 + 2] = v.z; Xs[kr][f * 4 + 3] = v.w;
  }
  __syncthreads();
  unsigned short* ob = xT + (size_t)b * (HW * DIMC);
#pragma unroll
  for (int i = 0; i < 2; ++i) {
    int slot = tid + i * 256;
    int sr = slot >> 3, g8 = slot & 7;
    unsigned short pk[8];
#pragma unroll
    for (int j = 0; j < 8; ++j) pk[j] = f2b(Xs[g8 * 8 + j][sr]);
    *(uint4*)&ob[(size_t)(s0 + sr) * DIMC + k0 + g8 * 8] = *(uint4*)pk;
  }
}

// ---------------- K0b: qkv_w -> bf16 A-fragment-swizzled ----------------
__global__ __launch_bounds__(256) void cast_qw(const float* __restrict__ qw,
                                               unsigned short* __restrict__ qwf) {
  int t = blockIdx.x * 256 + threadIdx.x;  // 6144
  int lane = t & 63;
  int cell = t >> 6;  // band*8 + c32
  int m = lane & 15, g = lane >> 4;
  int band = cell >> 3, c32 = cell & 7;
  int j = band * 16 + m;
  int k = c32 * 32 + g * 8;
  unsigned short pk[8];
#pragma unroll
  for (int i = 0; i < 8; ++i) pk[i] = f2b(qw[j * 256 + k + i]);
  *(uint4*)&qwf[(size_t)t * 8] = *(uint4*)pk;
}

// ---------------- K0c: proj_w (256,64) -> bf16 A-fragment-swizzled ----------------
__global__ __launch_bounds__(256) void cast_pw(const float* __restrict__ pw,
                                               unsigned short* __restrict__ pwf) {
  int t = blockIdx.x * 256 + threadIdx.x;  // 2048
  int lane = t & 63;
  int cell = t >> 6;  // band*2 + c32
  int m = lane & 15, g = lane >> 4;
  int band = cell >> 1, c32 = cell & 1;
  int d = band * 16 + m;
  int j = c32 * 32 + g * 8;
  unsigned short pk[8];
#pragma unroll
  for (int i = 0; i < 8; ++i) pk[i] = f2b(pw[d * 64 + j + i]);
  *(uint4*)&pwf[(size_t)t * 8] = *(uint4*)pk;
}

// ---------------- K1: qkv GEMM via bf16 MFMA ----------------
__global__ __launch_bounds__(256) void qkv_mfma(const unsigned short* __restrict__ xT,
                                                const unsigned short* __restrict__ qwf,
                                                const float* __restrict__ qb,
                                                unsigned short* __restrict__ qkvt) {
  __shared__ unsigned short Bs[128 * 256];
  const int b = blockIdx.y;
  const int s_blk = blockIdx.x * 128;
  const int tid = threadIdx.x;
  const int wave = tid >> 6, lane = tid & 63;

  {
    const int row_in = lane >> 5, cst = lane & 31;
#pragma unroll
    for (int ii = 0; ii < 16; ++ii) {
      int i = wave * 16 + ii;
      int s_row = 2 * i + row_in;
      int mem_chunk = (cst & 24) | ((cst ^ s_row) & 7);
      const unsigned short* src =
          xT + ((size_t)b * HW + s_blk + s_row) * DIMC + mem_chunk * 8;
      async_copy16(src, (char*)Bs + i * 1024);
    }
  }
  __syncthreads();

  f32x4 acc[3][8];
#pragma unroll
  for (int t = 0; t < 3; ++t)
#pragma unroll
    for (int st = 0; st < 8; ++st) acc[t][st] = (f32x4){0.f, 0.f, 0.f, 0.f};

  const int n = lane & 15, g = lane >> 4;
#pragma unroll
  for (int c32 = 0; c32 < 8; ++c32) {
    bf16x8 af[3];
#pragma unroll
    for (int t = 0; t < 3; ++t) {
      int band = wave * 3 + t;
      af[t] = *(const bf16x8*)(qwf + ((size_t)(band * 8 + c32) * 64 + lane) * 8);
    }
#pragma unroll
    for (int st = 0; st < 8; ++st) {
      int s_row = st * 16 + n;
      int mc = c32 * 4 + g;
      int stc = (mc & 24) | ((mc ^ s_row) & 7);
      bf16x8 bf = *(const bf16x8*)&Bs[s_row * 256 + stc * 8];
#pragma unroll
      for (int t = 0; t < 3; ++t)
        acc[t][st] = __builtin_amdgcn_mfma_f32_16x16x32_bf16(af[t], bf, acc[t][st], 0, 0, 0);
    }
  }

  unsigned short* ob = qkvt + (size_t)b * (NQKV * HW);
#pragma unroll
  for (int t = 0; t < 3; ++t) {
    int j0 = (wave * 3 + t) * 16 + g * 4;
#pragma unroll
    for (int st = 0; st < 8; ++st) {
      int s = s_blk + st * 16 + n;
#pragma unroll
      for (int r = 0; r < 4; ++r) {
        float v = acc[t][st][r] + qb[j0 + r];
        ob[(size_t)(j0 + r) * HW + s] = f2b(v);
      }
    }
  }
}

// ---------------- K2 v3: 2-pixel/thread fused attn, writes aoT bf16 ----------------
// Block: 8 waves = 8 channels of one (b,head); tile 8x16 pixels; thread owns
// pixels (ly,lx) and (ly+4,lx) -> float2 math (v_pk_fma-friendly).
__global__ __launch_bounds__(512, 2) void attn_kernel(const unsigned short* __restrict__ qkvt,
                                                      const float* __restrict__ dcb,
                                                      const float* __restrict__ w1,
                                                      const float* __restrict__ dc1b,
                                                      const float* __restrict__ rpb,
                                                      unsigned short* __restrict__ aoT) {
  __shared__ float hal[16][10][20];           // kk(0-7)/vv(8-15) halos, rows 10, pad 20
  __shared__ float plog[8][9][128];           // per-channel partial logits (2 px sets)
  __shared__ __align__(16) float wA[8][84];
  __shared__ float dsum[72];
  __shared__ float rpbn[9];
  __shared__ unsigned short ot[128][8];       // transpose buffer for aoT write

  const int bn = blockIdx.x;   // b*8+n
  const int tile = blockIdx.y; // 0..31 : 8 y-tiles x 4 x-tiles
  const int b = bn >> 3, n = bn & 7;
  const int h0 = (tile >> 2) * 8, w0 = (tile & 3) * 16;
  const int tid = threadIdx.x;
  const int c = tid >> 6, lane = tid & 63;
  const int ly = lane >> 4, lx = lane & 15;
  const int s0 = (h0 + ly) * 64 + (w0 + lx);
  const int s1 = s0 + 256;  // +4 rows
  const unsigned short* fb = qkvt + ((size_t)b * NQKV + n * 24) * HW;

  // stage halos: 16 bufs x 10 x 18 = 2880
  for (int e = tid; e < 2880; e += 512) {
    int cb = e / 180;
    int rem = e - cb * 180;
    int y = rem / 18, xx = rem - y * 18;
    int gy = h0 - 1 + y, gx = w0 - 1 + xx;
    float v = 0.f;
    if ((unsigned)gy < 64u && (unsigned)gx < 64u)
      v = b2f(fb[(size_t)(8 + cb) * HW + gy * 64 + gx]);
    hal[cb][y][xx] = v;
  }
  for (int e = tid; e < 648; e += 512) {
    int cc = e / 81;
    wA[cc][e - cc * 81] = w1[e];
  }
  if (tid < 72) dsum[tid] = dcb[tid] + dc1b[tid];
  else if (tid >= 128 && tid < 137) rpbn[tid - 128] = rpb[n * 9 + (tid - 128)];

  float qc0 = SCALE * b2f(fb[(size_t)c * HW + s0]);
  float qc1 = SCALE * b2f(fb[(size_t)c * HW + s1]);
  __syncthreads();

  float Af[81];
#pragma unroll
  for (int i = 0; i < 20; ++i) {
    float4 v = *(const float4*)&wA[c][i * 4];
    Af[i * 4 + 0] = v.x; Af[i * 4 + 1] = v.y;
    Af[i * 4 + 2] = v.z; Af[i * 4 + 3] = v.w;
  }
  Af[80] = wA[c][80];
#pragma unroll
  for (int p = 0; p < 9; ++p) Af[p * 9 + p] += 1.f;

  // ---- K phase (both pixels) ----
  {
    float2 t[9];
#pragma unroll
    for (int dy = 0; dy < 3; ++dy)
#pragma unroll
      for (int dx = 0; dx < 3; ++dx)
        t[dy * 3 + dx] = make_float2(hal[c][ly + dy][lx + dx],
                                     hal[c][ly + 4 + dy][lx + dx]);
#pragma unroll
    for (int p = 0; p < 9; ++p) {
      float base = dsum[c * 9 + p] + rpbn[p];
      float kx = base, ky = base;
#pragma unroll
      for (int rs = 0; rs < 9; ++rs) {
        kx = fmaf(Af[p * 9 + rs], t[rs].x, kx);
        ky = fmaf(Af[p * 9 + rs], t[rs].y, ky);
      }
      plog[c][p][lane] = qc0 * kx;
      plog[c][p][lane + 64] = qc1 * ky;
    }
  }
  __syncthreads();

  // ---- reduce over channels: 9 p x 128 px ----
  for (int it = tid; it < 1152; it += 512) {
    int p = it >> 7, px = it & 127;
    float sum = plog[0][p][px] + plog[1][p][px] + plog[2][p][px] + plog[3][p][px] +
                plog[4][p][px] + plog[5][p][px] + plog[6][p][px] + plog[7][p][px];
    plog[0][p][px] = sum;
  }
  __syncthreads();

  // ---- softmax: every thread, both pixels (redundant across waves, no extra sync) ----
  float ax[9], ay[9];
  {
    float mx = -1e30f, my = -1e30f;
#pragma unroll
    for (int p = 0; p < 9; ++p) {
      ax[p] = plog[0][p][lane];
      ay[p] = plog[0][p][lane + 64];
      mx = fmaxf(mx, ax[p]); my = fmaxf(my, ay[p]);
    }
    float dx = 0.f, dy = 0.f;
#pragma unroll
    for (int p = 0; p < 9; ++p) {
      ax[p] = __expf(ax[p] - mx); dx += ax[p];
      ay[p] = __expf(ay[p] - my); dy += ay[p];
    }
    float ix = 1.f / dx, iy = 1.f / dy;
#pragma unroll
    for (int p = 0; p < 9; ++p) { ax[p] *= ix; ay[p] *= iy; }
  }

  // ---- V phase (both pixels) ----
  {
    float2 t[9];
#pragma unroll
    for (int dy = 0; dy < 3; ++dy)
#pragma unroll
      for (int dx = 0; dx < 3; ++dx)
        t[dy * 3 + dx] = make_float2(hal[8 + c][ly + dy][lx + dx],
                                     hal[8 + c][ly + 4 + dy][lx + dx]);
    float ocx = 0.f, ocy = 0.f;
#pragma unroll
    for (int p = 0; p < 9; ++p) {
      float base = dsum[c * 9 + p];
      float vx = base, vy = base;
#pragma unroll
      for (int rs = 0; rs < 9; ++rs) {
        vx = fmaf(Af[p * 9 + rs], t[rs].x, vx);
        vy = fmaf(Af[p * 9 + rs], t[rs].y, vy);
      }
      ocx = fmaf(ax[p], vx, ocx);
      ocy = fmaf(ay[p], vy, ocy);
    }
    ot[lane][c] = f2b(ocx);
    ot[lane + 64][c] = f2b(ocy);
  }
  __syncthreads();

  // ---- write aoT[b][s][j=n*8..n*8+7] (16B per pixel) ----
  if (c < 2) {
    int p = c * 64 + lane;
    uint4 val = *(const uint4*)&ot[p][0];
    int sp = (h0 + (p >> 4)) * 64 + w0 + (p & 15);
    *(uint4*)&aoT[((size_t)b * HW + sp) * 64 + n * 8] = val;
  }
}

// ---------------- K3: proj GEMM via bf16 MFMA ----------------
// out(256d x 128s per block) = pw(256x64) * aoT^T; K=64. 4 waves x 4 d-bands x 8 s-tiles.
__global__ __launch_bounds__(256) void proj_mfma(const unsigned short* __restrict__ aoT,
                                                 const unsigned short* __restrict__ pwf,
                                                 const float* __restrict__ pb,
                                                 float* __restrict__ out) {
  __shared__ unsigned short Bs[128 * 64];  // rows 128B, 8 chunks XOR-swizzled
  const int b = blockIdx.y;
  const int s_blk = blockIdx.x * 128;
  const int tid = threadIdx.x;
  const int wave = tid >> 6, lane = tid & 63;

  {
    const int slot = lane & 7, rsub = lane >> 3;
#pragma unroll
    for (int ii = 0; ii < 4; ++ii) {
      int i = wave * 4 + ii;
      int row = 8 * i + rsub;
      int mem_chunk = slot ^ rsub;
      const unsigned short* src =
          aoT + ((size_t)b * HW + s_blk + row) * 64 + mem_chunk * 8;
      async_copy16(src, (char*)Bs + i * 1024);
    }
  }
  __syncthreads();

  f32x4 acc[4][8];
#pragma unroll
  for (int t = 0; t < 4; ++t)
#pragma unroll
    for (int st = 0; st < 8; ++st) acc[t][st] = (f32x4){0.f, 0.f, 0.f, 0.f};

  const int n = lane & 15, g = lane >> 4;
#pragma unroll
  for (int c32 = 0; c32 < 2; ++c32) {
    bf16x8 af[4];
#pragma unroll
    for (int t = 0; t < 4; ++t) {
      int band = wave * 4 + t;
      af[t] = *(const bf16x8*)(pwf + ((size_t)(band * 2 + c32) * 64 + lane) * 8);
    }
#pragma unroll
    for (int st = 0; st < 8; ++st) {
      int s_row = st * 16 + n;
      int mc = c32 * 4 + g;
      int stc = mc ^ (s_row & 7);
      bf16x8 bf = *(const bf16x8*)&Bs[s_row * 64 + stc * 8];
#pragma unroll
      for (int t = 0; t < 4; ++t)
        acc[t][st] = __builtin_amdgcn_mfma_f32_16x16x32_bf16(af[t], bf, acc[t][st], 0, 0, 0);
    }
  }

  float bias[4][4];
#pragma unroll
  for (int t = 0; t < 4; ++t)
#pragma unroll
    for (int r = 0; r < 4; ++r) bias[t][r] = pb[(wave * 4 + t) * 16 + g * 4 + r];

  float* ob = out + ((size_t)b << 20);
#pragma unroll
  for (int t = 0; t < 4; ++t) {
    int d0 = (wave * 4 + t) * 16 + g * 4;
#pragma unroll
    for (int st = 0; st < 8; ++st) {
      int s = s_blk + st * 16 + n;
#pragma unroll
      for (int r = 0; r < 4; ++r)
        ob[(size_t)(d0 + r) * HW + s] = acc[t][st][r] + bias[t][r];
    }
  }
}

extern "C" void kernel_launch(void* const* d_in, const int* in_sizes, int n_in,
                              void* d_out, int out_size, void* d_ws, size_t ws_size,
                              hipStream_t stream) {
  (void)in_sizes; (void)n_in; (void)out_size; (void)ws_size;
  const float* x    = (const float*)d_in[0];
  const float* qw   = (const float*)d_in[5];
  const float* qb   = (const float*)d_in[6];
  const float* dcb  = (const float*)d_in[7];
  const float* w1   = (const float*)d_in[8];
  const float* dc1b = (const float*)d_in[9];
  const float* rpb  = (const float*)d_in[10];
  const float* pw   = (const float*)d_in[11];
  const float* pb   = (const float*)d_in[12];

  // Workspace (time-multiplexed, 64 MiB total = proven-safe R0 size):
  // [0, 25165824)            qkvt bf16 (B,192,4096)          qkv -> attn
  // [25165824, 33554432)     qwf (cast_qw -> qkv, dead after) THEN aoT bf16 (attn -> proj)
  // [33554432, 67108864)     xT bf16 (cast_xT -> qkv, dead)   THEN pwf (cast_pw -> proj)
  unsigned short* qkvt = (unsigned short*)d_ws;
  unsigned short* qwf  = (unsigned short*)((char*)d_ws + 25165824);
  unsigned short* aoT  = (unsigned short*)((char*)d_ws + 25165824);
  unsigned short* xT   = (unsigned short*)((char*)d_ws + 33554432);
  unsigned short* pwf  = (unsigned short*)((char*)d_ws + 33554432);

  cast_qw<<<24, 256, 0, stream>>>(qw, qwf);
  cast_xT<<<dim3(64, 4, BB), 256, 0, stream>>>(x, xT);
  qkv_mfma<<<dim3(32, BB), 256, 0, stream>>>(xT, qwf, qb, qkvt);
  cast_pw<<<8, 256, 0, stream>>>(pw, pwf);
  attn_kernel<<<dim3(BB * NHEAD, 32), 512, 0, stream>>>(qkvt, dcb, w1, dc1b, rpb, aoT);
  proj_mfma<<<dim3(32, BB), 256, 0, stream>>>(aoT, pwf, pb, (float*)d_out);
}